// Round 18
// baseline (489.963 us; speedup 1.0000x reference)
//
#include <hip/hip_runtime.h>
#include <stdint.h>

#define FD   256
#define NA   8649
#define MT   69192          // 8*NA flattened rows
#define LSTR 8704
#define PB   (33*33*256)

typedef unsigned short ushort_t;
typedef short bf16x8 __attribute__((ext_vector_type(8)));
typedef float f32x4  __attribute__((ext_vector_type(4)));

#define SWZ(r) (((r) >> 2) & 3)

// ---------- bf16 helpers ----------
__device__ __forceinline__ unsigned short f2bf(float x) {
  unsigned int u = __float_as_uint(x);
  unsigned int r = (u + 0x7FFFu + ((u >> 16) & 1u)) >> 16;
  return (unsigned short)r;
}
__device__ __forceinline__ float bf2f(unsigned short h) {
  return __uint_as_float(((unsigned int)h) << 16);
}
__device__ __forceinline__ void dec2(float x, unsigned short& h, unsigned short& l) {
  h = f2bf(x);
  l = f2bf(x - bf2f(h));
}

__device__ __forceinline__ void gl2lds(const void* g, void* l) {
  __builtin_amdgcn_global_load_lds(
      (const __attribute__((address_space(1))) void*)g,
      (__attribute__((address_space(3))) void*)l, 16, 0, 0);
}

__device__ __forceinline__ bf16x8 fldq(const ushort_t* plane, int row, int qq) {
  return *(const bf16x8*)(plane + row*32 + ((qq ^ SWZ(row)) << 3));
}

__device__ __forceinline__ f32x4 mfma2(bf16x8 ah, bf16x8 bh, bf16x8 bl, f32x4 acc) {
  acc = __builtin_amdgcn_mfma_f32_16x16x32_bf16(ah, bl, acc, 0, 0, 0);
  acc = __builtin_amdgcn_mfma_f32_16x16x32_bf16(ah, bh, acc, 0, 0, 0);
  return acc;
}
__device__ __forceinline__ f32x4 mfma3(bf16x8 ah, bf16x8 al, bf16x8 bh, bf16x8 bl, f32x4 acc) {
  acc = __builtin_amdgcn_mfma_f32_16x16x32_bf16(al, bh, acc, 0, 0, 0);
  acc = __builtin_amdgcn_mfma_f32_16x16x32_bf16(ah, bl, acc, 0, 0, 0);
  acc = __builtin_amdgcn_mfma_f32_16x16x32_bf16(ah, bh, acc, 0, 0, 0);
  return acc;
}

// ================= integral images =================
__global__ __launch_bounds__(256) void k_rowsum(const float* __restrict__ kin,
    const float* __restrict__ vin, float* __restrict__ Pk,
    float* __restrict__ Pk2, float* __restrict__ Pv) {
  int b = blockIdx.x >> 5, i = blockIdx.x & 31;
  int f = threadIdx.x;
  const float* kr = kin + ((size_t)b*1024 + i*32)*FD + f;
  const float* vr = vin + ((size_t)b*1024 + i*32)*FD + f;
  float sk = 0.f, sk2 = 0.f, sv = 0.f;
  size_t base = (size_t)b*PB + (size_t)(i+1)*33*FD + f;
  #pragma unroll
  for (int j = 0; j < 32; ++j) {
    float kv = kr[j*FD], vv = vr[j*FD];
    sk += kv; sk2 += kv*kv; sv += vv;
    size_t p = base + (size_t)(j+1)*FD;
    Pk[p] = sk; Pk2[p] = sk2; Pv[p] = sv;
  }
}

__global__ __launch_bounds__(256) void k_colsum(float* __restrict__ Pk,
    float* __restrict__ Pk2, float* __restrict__ Pv) {
  int j = blockIdx.x, b = blockIdx.y, f = threadIdx.x;
  float* P = (blockIdx.z == 0) ? Pk : (blockIdx.z == 1) ? Pk2 : Pv;
  size_t base = (size_t)b*PB + f;
  if (j == 0) {
    for (int i = 0; i < 33; ++i) P[base + (size_t)i*33*FD] = 0.f;
  } else {
    P[base + (size_t)j*FD] = 0.f;
    float a = 0.f;
    for (int i = 1; i <= 32; ++i) {
      size_t p = base + ((size_t)i*33 + j)*FD;
      a += P[p]; P[p] = a;
    }
  }
}

// ============ merged prep: decompq | LDS-transposed decompw | bias9 | tab ============
__global__ __launch_bounds__(256) void k_prep(const float* __restrict__ q,
    const float* __restrict__ W1, const float* __restrict__ W2,
    const float* __restrict__ eh, const float* __restrict__ ew,
    const float* __restrict__ b1,
    ushort_t* __restrict__ qh, ushort_t* __restrict__ ql,
    ushort_t* __restrict__ w1h, ushort_t* __restrict__ w1l,
    ushort_t* __restrict__ w2h, ushort_t* __restrict__ w2l,
    float* __restrict__ bias9, uint32_t* __restrict__ tab) {
  __shared__ float tile[64][65];
  int bx = blockIdx.x, t = threadIdx.x;
  if (bx < 1024) {                       // ---- decompq ----
    int i = (bx*256 + t) * 8;
    float4 v0 = *(const float4*)(q + i);
    float4 v1 = *(const float4*)(q + i + 4);
    float e[8] = {v0.x, v0.y, v0.z, v0.w, v1.x, v1.y, v1.z, v1.w};
    bf16x8 h8, l8;
    #pragma unroll
    for (int j = 0; j < 8; ++j) {
      unsigned short hu, lu; dec2(e[j], hu, lu);
      h8[j] = (short)hu; l8[j] = (short)lu;
    }
    *(bf16x8*)(qh + i) = h8;
    *(bf16x8*)(ql + i) = l8;
  } else if (bx < 1072) {                // ---- decompw: 64x64 LDS transpose tiles ----
    int tb = bx - 1024;
    const float* src; ushort_t* dh; ushort_t* dl; int K, k0, n0;
    if (tb < 32) { src = W1; dh = w1h; dl = w1l; K = 512; k0 = (tb>>2)*64; n0 = (tb&3)*64; }
    else { tb -= 32; src = W2; dh = w2h; dl = w2l; K = 256; k0 = (tb>>2)*64; n0 = (tb&3)*64; }
    int c = t & 63, r4 = t >> 6;
    #pragma unroll
    for (int i = 0; i < 16; ++i) {
      int r = i*4 + r4;
      tile[r][c] = src[(size_t)(k0+r)*FD + n0 + c];
    }
    __syncthreads();
    #pragma unroll
    for (int i = 0; i < 16; ++i) {
      int n = i*4 + r4;
      float x = tile[c][n];
      unsigned short hu, lu; dec2(x, hu, lu);
      dh[(size_t)(n0+n)*K + k0 + c] = hu;
      dl[(size_t)(n0+n)*K + k0 + c] = lu;
    }
  } else if (bx < 1081) {                // ---- bias9 ----
    int s = bx - 1072, c = t;
    int ah = s/3, aw = s - ah*3;
    float acc = b1[c];
    for (int j = 0; j < 128; ++j) acc += eh[ah*128 + j] * W1[(size_t)(512+j)*FD + c];
    for (int j = 0; j < 128; ++j) acc += ew[aw*128 + j] * W1[(size_t)(640+j)*FD + c];
    bias9[s*FD + c] = acc;
  } else {                               // ---- tab ----
    int a = (bx - 1081)*256 + t;
    if (a >= NA) return;
    const int offs[10] = {0,1024,2016,2976,3968,4929,5859,6819,7749,8649};
    int s = 0;
    #pragma unroll
    for (int i = 1; i < 9; ++i) s += (a >= offs[i]) ? 1 : 0;
    int ah = s/3, aw = s - ah*3;
    int idx = a - offs[s];
    int wc = 32 - aw;
    int r = idx / wc;
    int c = idx - r*wc;
    tab[a] = (uint32_t)(r | (c<<6) | (ah<<12) | (aw<<14));
  }
}

// ================= X features: mean|std -> bf16 [MT][512] =================
__global__ __launch_bounds__(256) void k_xfeat(const float* __restrict__ Pk,
    const float* __restrict__ Pk2, const uint32_t* __restrict__ tab,
    ushort_t* __restrict__ xh) {
  int t = threadIdx.x;
  int row0 = blockIdx.x * 16;
  for (int rr = 0; rr < 16; ++rr) {
    int gr = row0 + rr;
    if (gr >= MT) return;
    int bi = gr / NA;
    int a  = gr - bi*NA;
    uint32_t tb = tab[a];
    int r1 = tb & 63, c1 = (tb>>6)&63, ah=(tb>>12)&3, aw=(tb>>14)&3;
    int r2 = r1+ah+1, c2 = c1+aw+1;
    const float* PKb  = Pk  + (size_t)bi*PB + t;
    const float* PK2b = Pk2 + (size_t)bi*PB + t;
    int i11=(r1*33+c1)*FD, i12=(r1*33+c2)*FD, i21=(r2*33+c1)*FD, i22=(r2*33+c2)*FD;
    float s  = PKb[i22]  - PKb[i12]  - PKb[i21]  + PKb[i11];
    float s2 = PK2b[i22] - PK2b[i12] - PK2b[i21] + PK2b[i11];
    float inv = 1.0f/(float)((ah+1)*(aw+1));
    float mean = s * inv;
    float sd = sqrtf(fabsf(s2*inv - mean*mean) + 1e-6f);
    xh[(size_t)gr*512 + t]       = f2bf(mean);
    xh[(size_t)gr*512 + 256 + t] = f2bf(sd);
  }
}

// ================= l1: h = relu(X @ W1t + bias9), BM=128 BN=256 BK=32, 512thr =================
__global__ __launch_bounds__(512) void k_l1(
    const ushort_t* __restrict__ xh, const ushort_t* __restrict__ w1h,
    const ushort_t* __restrict__ w1l, const float* __restrict__ bias9g,
    const uint32_t* __restrict__ tab, ushort_t* __restrict__ hh) {
  __shared__ __align__(16) char SM[81920];     // 2 bufs x (A 8K + BH 16K + BL 16K)
  ushort_t* SU = (ushort_t*)SM;
  int t = threadIdx.x, lane = t & 63, wid = t >> 6;
  int wr = wid >> 2, wc = wid & 3;
  int row0 = blockIdx.x * 128;

  auto stage = [&](int s, int kc) {
    ushort_t* base = SU + s*20480;
    int r = wid*16 + (lane >> 2);
    int q = lane & 3;
    int rr = row0 + r; if (rr > MT-1) rr = MT-1;
    gl2lds(xh + (size_t)rr*512 + kc + ((q ^ SWZ(r)) << 3), base + wid*512);
    #pragma unroll
    for (int i = 0; i < 2; ++i) {
      int g = 2*wid + i;
      int r2 = g*16 + (lane >> 2);
      int off = (q ^ SWZ(r2)) << 3;
      gl2lds(w1h + (size_t)r2*512 + kc + off, base + 4096  + g*512);
      gl2lds(w1l + (size_t)r2*512 + kc + off, base + 12288 + g*512);
    }
  };

  f32x4 acc[4][4];
  #pragma unroll
  for (int i = 0; i < 4; ++i)
    #pragma unroll
    for (int j = 0; j < 4; ++j) acc[i][j] = (f32x4)0.f;

  stage(0, 0);
  __syncthreads();
  int cur = 0;
  for (int step = 0; step < 16; ++step) {
    if (step < 15) stage(cur ^ 1, (step+1)*32);
    const ushort_t* SA  = SU + cur*20480;
    const ushort_t* SBH = SA + 4096;
    const ushort_t* SBL = SA + 12288;
    int qq = lane >> 4;
    bf16x8 a_[4], bh_[4], bl_[4];
    #pragma unroll
    for (int i = 0; i < 4; ++i) {
      a_[i]  = fldq(SA,  wr*64 + i*16 + (lane & 15), qq);
      bh_[i] = fldq(SBH, wc*64 + i*16 + (lane & 15), qq);
      bl_[i] = fldq(SBL, wc*64 + i*16 + (lane & 15), qq);
    }
    #pragma unroll
    for (int mt = 0; mt < 4; ++mt)
      #pragma unroll
      for (int nt = 0; nt < 4; ++nt)
        acc[mt][nt] = mfma2(a_[mt], bh_[nt], bl_[nt], acc[mt][nt]);
    if (step < 15) { __syncthreads(); cur ^= 1; }
  }

  #pragma unroll
  for (int mt = 0; mt < 4; ++mt) {
    int lrowb = wr*64 + mt*16 + (lane >> 4)*4;
    #pragma unroll
    for (int r = 0; r < 4; ++r) {
      int grow = row0 + lrowb + r;
      if (grow < MT) {
        int a = grow % NA;
        uint32_t tb = tab[a];
        int seg = ((tb>>12)&3)*3 + ((tb>>14)&3);
        const float* bseg = bias9g + seg*FD;
        #pragma unroll
        for (int nt = 0; nt < 4; ++nt) {
          int col = wc*64 + nt*16 + (lane & 15);
          float hv = fmaxf(acc[mt][nt][r] + bseg[col], 0.f);
          hh[(size_t)grow*FD + col] = f2bf(hv);
        }
      }
    }
  }
}

// ================= l2: k_area = h @ W2t + b2 -> hi/lo, BM=128 BN=256 =================
__global__ __launch_bounds__(512) void k_l2(
    const ushort_t* __restrict__ hh, const ushort_t* __restrict__ w2h,
    const ushort_t* __restrict__ w2l, const float* __restrict__ b2,
    ushort_t* __restrict__ kh, ushort_t* __restrict__ kl) {
  __shared__ __align__(16) char SM[81920];
  ushort_t* SU = (ushort_t*)SM;
  int t = threadIdx.x, lane = t & 63, wid = t >> 6;
  int wr = wid >> 2, wc = wid & 3;
  int row0 = blockIdx.x * 128;

  auto stage = [&](int s, int kc) {
    ushort_t* base = SU + s*20480;
    int r = wid*16 + (lane >> 2);
    int q = lane & 3;
    int rr = row0 + r; if (rr > MT-1) rr = MT-1;
    gl2lds(hh + (size_t)rr*FD + kc + ((q ^ SWZ(r)) << 3), base + wid*512);
    #pragma unroll
    for (int i = 0; i < 2; ++i) {
      int g = 2*wid + i;
      int r2 = g*16 + (lane >> 2);
      int off = (q ^ SWZ(r2)) << 3;
      gl2lds(w2h + (size_t)r2*FD + kc + off, base + 4096  + g*512);
      gl2lds(w2l + (size_t)r2*FD + kc + off, base + 12288 + g*512);
    }
  };

  f32x4 acc[4][4];
  #pragma unroll
  for (int i = 0; i < 4; ++i)
    #pragma unroll
    for (int j = 0; j < 4; ++j) acc[i][j] = (f32x4)0.f;

  stage(0, 0);
  __syncthreads();
  int cur = 0;
  for (int step = 0; step < 8; ++step) {
    if (step < 7) stage(cur ^ 1, (step+1)*32);
    const ushort_t* SA  = SU + cur*20480;
    const ushort_t* SBH = SA + 4096;
    const ushort_t* SBL = SA + 12288;
    int qq = lane >> 4;
    bf16x8 a_[4], bh_[4], bl_[4];
    #pragma unroll
    for (int i = 0; i < 4; ++i) {
      a_[i]  = fldq(SA,  wr*64 + i*16 + (lane & 15), qq);
      bh_[i] = fldq(SBH, wc*64 + i*16 + (lane & 15), qq);
      bl_[i] = fldq(SBL, wc*64 + i*16 + (lane & 15), qq);
    }
    #pragma unroll
    for (int mt = 0; mt < 4; ++mt)
      #pragma unroll
      for (int nt = 0; nt < 4; ++nt)
        acc[mt][nt] = mfma2(a_[mt], bh_[nt], bl_[nt], acc[mt][nt]);
    if (step < 7) { __syncthreads(); cur ^= 1; }
  }

  #pragma unroll
  for (int mt = 0; mt < 4; ++mt) {
    int lrowb = wr*64 + mt*16 + (lane >> 4)*4;
    #pragma unroll
    for (int r = 0; r < 4; ++r) {
      int grow = row0 + lrowb + r;
      if (grow < MT) {
        #pragma unroll
        for (int nt = 0; nt < 4; ++nt) {
          int col = wc*64 + nt*16 + (lane & 15);
          float kv = acc[mt][nt][r] + b2[col];
          unsigned short hu, lu; dec2(kv, hu, lu);
          kh[(size_t)grow*FD + col] = hu;
          kl[(size_t)grow*FD + col] = lu;
        }
      }
    }
  }
}

// === logits: 1024thr/16 waves, 256x256 tile BK=32 dbuf(128KB), -inf pad, XCD swizzle ===
__global__ __launch_bounds__(1024, 1) void k_logits(
    const ushort_t* __restrict__ qh, const ushort_t* __restrict__ ql,
    const ushort_t* __restrict__ kh, const ushort_t* __restrict__ kl,
    float* __restrict__ logits, int bbase, int nwg) {
  __shared__ __align__(16) ushort_t SU[2][32768];  // 64KB/buf: Ah|Al|Bh|Bl (8192 each)
  int t = threadIdx.x, lane = t & 63, wid = t >> 6;
  int wr = wid >> 3, wc = wid & 7;                 // 2x8 wave grid, 128x32 per wave
  // XCD-aware bijective swizzle (nwg = 136*cc, always % 8 == 0)
  int bx0 = blockIdx.x;
  int bx = (bx0 & 7) * (nwg >> 3) + (bx0 >> 3);
  int bc = bx / 136;
  int r5 = bx - bc*136;
  int mb = r5 / 34, ab = r5 - mb*34;
  int m0 = mb*256, a0 = ab*256;
  int b = bbase + bc;
  size_t qbase = (size_t)b*1024*FD;
  size_t kbase = (size_t)b*NA*FD;
  float* logW = logits + (size_t)bc*1024*LSTR;

  auto stage = [&](int s, int kc) {
    ushort_t* base = &SU[s][0];
    int g = wid;                          // 0..15, one wave-load per plane
    int ch = g*64 + lane;                 // chunk id (1024 per plane)
    int rr = ch >> 2, sl = ch & 3;
    int off = (sl ^ SWZ(rr)) << 3;
    gl2lds(qh + qbase + (size_t)(m0+rr)*FD + kc + off, base + g*512);
    gl2lds(ql + qbase + (size_t)(m0+rr)*FD + kc + off, base + 8192 + g*512);
    int ar = a0 + rr; if (ar > NA-1) ar = NA-1;
    gl2lds(kh + kbase + (size_t)ar*FD + kc + off, base + 16384 + g*512);
    gl2lds(kl + kbase + (size_t)ar*FD + kc + off, base + 24576 + g*512);
  };

  f32x4 acc[8][2];
  #pragma unroll
  for (int i = 0; i < 8; ++i)
    #pragma unroll
    for (int j = 0; j < 2; ++j) acc[i][j] = (f32x4)0.f;

  stage(0, 0);
  __syncthreads();
  int cur = 0;
  for (int step = 0; step < 8; ++step) {
    if (step < 7) stage(cur ^ 1, (step+1)*32);
    const ushort_t* Ah = &SU[cur][0];
    const ushort_t* Al = Ah + 8192;
    const ushort_t* Bh = Ah + 16384;
    const ushort_t* Bl = Ah + 24576;
    int qq = lane >> 4;
    bf16x8 bhf[2], blf[2];
    #pragma unroll
    for (int nt = 0; nt < 2; ++nt) {
      int rb = wc*32 + nt*16 + (lane & 15);
      bhf[nt] = fldq(Bh, rb, qq);
      blf[nt] = fldq(Bl, rb, qq);
    }
    #pragma unroll
    for (int mt = 0; mt < 8; ++mt) {
      int ra = wr*128 + mt*16 + (lane & 15);
      bf16x8 ahf = fldq(Ah, ra, qq);
      bf16x8 alf = fldq(Al, ra, qq);
      #pragma unroll
      for (int nt = 0; nt < 2; ++nt)
        acc[mt][nt] = mfma3(ahf, alf, bhf[nt], blf[nt], acc[mt][nt]);
    }
    if (step < 7) { __syncthreads(); cur ^= 1; }
  }

  const float NINF = -__builtin_inff();
  #pragma unroll
  for (int mt = 0; mt < 8; ++mt) {
    int m = m0 + wr*128 + mt*16 + (lane >> 4)*4;
    #pragma unroll
    for (int nt = 0; nt < 2; ++nt) {
      int col = a0 + wc*32 + nt*16 + (lane & 15);
      bool ok = (col < NA);
      #pragma unroll
      for (int r = 0; r < 4; ++r)
        logW[(size_t)(m+r)*LSTR + col] = ok ? acc[mt][nt][r] : NINF;
    }
  }
}

// ====== final: 512-thr float bucketed top-64 (SCALE=8) + 8-group float4 PV ======
__device__ __forceinline__ uint32_t f2key(float x) {
  uint32_t u = __float_as_uint(x);
  return (u & 0x80000000u) ? ~u : (u | 0x80000000u);
}
__device__ __forceinline__ float key2f(uint32_t k) {
  uint32_t u = (k & 0x80000000u) ? (k & 0x7FFFFFFFu) : ~k;
  return __uint_as_float(u);
}

__global__ __launch_bounds__(512) void k_final(const float* __restrict__ logits,
    const float* __restrict__ Pv, const uint32_t* __restrict__ tab,
    float* __restrict__ outp, int bbase) {
  __shared__ int   hist[256];
  __shared__ float redf[8];
  __shared__ int   seli[2];
  __shared__ int   lst[192];
  __shared__ float lw[192];
  __shared__ int4  offs[192];
  __shared__ float accvB[8][256];
  __shared__ int   shcnt;
  __shared__ float cands_v[256];
  __shared__ int   cands_i[256];
  __shared__ int   ncand;
  __shared__ float thrs;
  int t = threadIdx.x;
  int qrow = blockIdx.x & 1023;
  int bc = blockIdx.x >> 10;
  int b = bbase + bc;
  const float* row = logits + ((size_t)bc*1024 + qrow)*LSTR;

  // ---- vectorized row load: v[4j+k] = row[j*2048 + 4t + k], v[16] = row[8192+t] ----
  float v[17];
  {
    const float4* row4 = (const float4*)row;
    float4 x0 = row4[t], x1 = row4[t+512], x2 = row4[t+1024], x3 = row4[t+1536];
    v[0]=x0.x; v[1]=x0.y; v[2]=x0.z; v[3]=x0.w;
    v[4]=x1.x; v[5]=x1.y; v[6]=x1.z; v[7]=x1.w;
    v[8]=x2.x; v[9]=x2.y; v[10]=x2.z; v[11]=x2.w;
    v[12]=x3.x; v[13]=x3.y; v[14]=x3.z; v[15]=x3.w;
    v[16]=row[8192 + t];
  }
  float vmax = v[0];
  #pragma unroll
  for (int i = 1; i < 17; ++i) vmax = fmaxf(vmax, v[i]);
  #pragma unroll
  for (int off = 32; off >= 1; off >>= 1) vmax = fmaxf(vmax, __shfl_xor(vmax, off));
  if ((t & 63) == 0) redf[t >> 6] = vmax;
  if (t < 256) hist[t] = 0;
  if (t == 0) { seli[0] = -1; ncand = 0; shcnt = 0; }
  __syncthreads();
  float maxv = fmaxf(fmaxf(fmaxf(redf[0],redf[1]),fmaxf(redf[2],redf[3])),
                     fmaxf(fmaxf(redf[4],redf[5]),fmaxf(redf[6],redf[7])));

  // ---- pass 1: near-max bucketed histogram (bin width 1/8, range maxv-32..maxv) ----
  const float SCALE = 8.0f;
  int bins[17];
  #pragma unroll
  for (int i = 0; i < 17; ++i) {
    int bin = (int)((maxv - v[i]) * SCALE);
    bins[i] = bin;
    if ((unsigned)bin < 256u) atomicAdd(&hist[bin], 1);
  }
  __syncthreads();
  // ---- scan: first bin where cumulative >= 64; rank within bin ----
  if (t < 64) {
    int b0 = t*4;
    int h0 = hist[b0], h1 = hist[b0+1], h2 = hist[b0+2], h3 = hist[b0+3];
    int gsum = h0+h1+h2+h3;
    int pre = gsum;
    #pragma unroll
    for (int d = 1; d < 64; d <<= 1) {
      int o = __shfl_up(pre, d);
      if (t >= d) pre += o;
    }
    pre -= gsum;                         // exclusive prefix (bins < b0)
    int c0 = pre+h0, c1 = c0+h1, c2 = c1+h2, c3 = c2+h3;
    int cc[4] = {c0, c1, c2, c3};
    int pv[4] = {pre, c0, c1, c2};
    #pragma unroll
    for (int j = 0; j < 4; ++j)
      if (cc[j] >= 64 && pv[j] < 64) { seli[0] = b0 + j; seli[1] = 64 - pv[j]; }
  }
  __syncthreads();
  int tb_bin = seli[0];
  int nc_bin = (tb_bin >= 0) ? hist[tb_bin] : 1000;
  bool fast = (tb_bin >= 0) && (nc_bin <= 256);
  if (fast) {
    int rnk = seli[1];
    // ---- merged collect: bins<tb selected directly; bin==tb -> candidates ----
    #pragma unroll
    for (int i = 0; i < 17; ++i) {
      int idx = (i < 16) ? ((i >> 2)*2048 + 4*t + (i & 3)) : (8192 + t);
      if (bins[i] < tb_bin) {
        int p = atomicAdd(&shcnt, 1);
        if (p < 192) { lst[p] = idx; lw[p] = expf(v[i] - maxv); }
      } else if (bins[i] == tb_bin) {
        int p = atomicAdd(&ncand, 1);
        cands_v[p] = v[i]; cands_i[p] = idx;
      }
    }
    __syncthreads();
    // ---- exact rank among candidates: thr = rnk-th largest ----
    if (t < nc_bin) {
      float ck = cands_v[t];
      int ge = 0, gt = 0;
      for (int j = 0; j < nc_bin; ++j) {
        float cj = cands_v[j];
        ge += (cj >= ck) ? 1 : 0;
        gt += (cj >  ck) ? 1 : 0;
      }
      if (ge >= rnk && gt < rnk) thrs = ck;
    }
    __syncthreads();
    float thrf = thrs;
    // ---- append candidates >= thr (tiny pass over nc only) ----
    for (int j = t; j < nc_bin; j += 512) {
      if (cands_v[j] >= thrf) {
        int p = atomicAdd(&shcnt, 1);
        if (p < 192) { lst[p] = cands_i[j]; lw[p] = expf(cands_v[j] - maxv); }
      }
    }
  } else {
    // ---- fallback: full radix-256 select on monotone keys ----
    uint32_t prefix = 0; int need = 64;
    for (int rd = 0; rd < 4; ++rd) {
      int shift = 24 - rd*8;
      uint32_t pmask = (rd == 0) ? 0u : (0xFFFFFFFFu << (shift + 8));
      if (t < 256) hist[t] = 0;
      __syncthreads();
      #pragma unroll
      for (int i = 0; i < 17; ++i) {
        uint32_t ky = f2key(v[i]);
        if ((ky & pmask) == prefix)
          atomicAdd(&hist[(ky >> shift) & 255], 1);
      }
      __syncthreads();
      if (t < 64) {
        int b0 = t*4;
        int h0 = hist[b0], h1 = hist[b0+1], h2 = hist[b0+2], h3 = hist[b0+3];
        int s3 = h3, s2 = h2 + s3, s1 = h1 + s2, s0 = h0 + s1;
        int suf = s0;
        #pragma unroll
        for (int d = 1; d < 64; d <<= 1) {
          int o = __shfl_down(suf, d);
          if (t + d < 64) suf += o;
        }
        int above = suf - s0;
        int cg[5] = { above + s0, above + s1, above + s2, above + s3, above };
        #pragma unroll
        for (int j = 0; j < 4; ++j)
          if (cg[j] >= need && cg[j+1] < need) { seli[0] = b0 + j; seli[1] = need - cg[j+1]; }
      }
      __syncthreads();
      prefix |= ((uint32_t)seli[0]) << shift;
      need = seli[1];
      __syncthreads();
    }
    float thrf = key2f(prefix);
    #pragma unroll
    for (int i = 0; i < 17; ++i) {
      if (v[i] >= thrf) {
        int p = atomicAdd(&shcnt, 1);
        if (p < 192) {
          int idx = (i < 16) ? ((i >> 2)*2048 + 4*t + (i & 3)) : (8192 + t);
          lst[p] = idx;
          lw[p]  = expf(v[i] - maxv);
        }
      }
    }
  }
  __syncthreads();
  int S = min(shcnt, 192);
  // ---- one-time offset precompute (t<S) + weight sum (t<64) ----
  if (t < S) {
    int a = lst[t];
    uint32_t tb = tab[a];
    int r1 = tb & 63, c1 = (tb>>6)&63, ah=(tb>>12)&3, aw=(tb>>14)&3;
    int r2 = r1+ah+1, c2 = c1+aw+1;
    offs[t] = make_int4((r1*33+c1)*FD, (r1*33+c2)*FD, (r2*33+c1)*FD, (r2*33+c2)*FD);
  }
  float ssum = 0.f;
  if (t < 64) {
    for (int i = t; i < S; i += 64) ssum += lw[i];
    #pragma unroll
    for (int off = 32; off >= 1; off >>= 1) ssum += __shfl_xor(ssum, off);
    if (t == 0) redf[0] = ssum;
  }
  __syncthreads();
  float inv = 1.0f / redf[0];
  // ---- PV gather: 8 wave-groups, float4 per lane, 2x unrolled ----
  int lf  = (t & 63) << 2;       // f base (float4)
  int grp = t >> 6;              // 0..7 (one wave per group)
  const float* Pvb = Pv + (size_t)b*PB + lf;
  float4 a4 = make_float4(0.f, 0.f, 0.f, 0.f);
  auto body = [&](int i) {
    int4 o = offs[i];
    float w = lw[i];
    float4 A = *(const float4*)(Pvb + o.x);
    float4 B = *(const float4*)(Pvb + o.y);
    float4 C = *(const float4*)(Pvb + o.z);
    float4 D = *(const float4*)(Pvb + o.w);
    a4.x += w * (D.x - B.x - C.x + A.x);
    a4.y += w * (D.y - B.y - C.y + A.y);
    a4.z += w * (D.z - B.z - C.z + A.z);
    a4.w += w * (D.w - B.w - C.w + A.w);
  };
  int i = grp;
  for (; i + 8 < S; i += 16) { body(i); body(i + 8); }
  if (i < S) body(i);
  *(float4*)&accvB[grp][lf] = a4;
  __syncthreads();
  if (t < 256) {
    float s = 0.f;
    #pragma unroll
    for (int g = 0; g < 8; ++g) s += accvB[g][t];
    outp[((size_t)b*1024 + qrow)*FD + t] = s * inv;
  }
}

// ================= launch =================
extern "C" void kernel_launch(void* const* d_in, const int* in_sizes, int n_in,
                              void* d_out, int out_size, void* d_ws, size_t ws_size,
                              hipStream_t stream) {
  const float* q  = (const float*)d_in[0];
  const float* k  = (const float*)d_in[1];
  const float* v  = (const float*)d_in[2];
  const float* eh = (const float*)d_in[3];
  const float* ew = (const float*)d_in[4];
  const float* W1 = (const float*)d_in[5];
  const float* b1 = (const float*)d_in[6];
  const float* W2 = (const float*)d_in[7];
  const float* b2 = (const float*)d_in[8];
  float* out = (float*)d_out;

  char* Wp = (char*)d_ws;
  size_t off = 0;
  auto alloc = [&](size_t bytes) -> char* {
    char* p = Wp + off; off += (bytes + 255) & ~(size_t)255; return p;
  };
  const size_t HBYTES = (size_t)MT*FD*2;        // 35,426,304
  const size_t LBYTES = (size_t)1024*LSTR*4;    // 35,651,584 per batch
  float*    Pv  = (float*)alloc((size_t)8*PB*4);
  ushort_t* qh  = (ushort_t*)alloc((size_t)8*1024*FD*2);
  ushort_t* ql  = (ushort_t*)alloc((size_t)8*1024*FD*2);
  ushort_t* w1h = (ushort_t*)alloc(131072*2);
  ushort_t* w1l = (ushort_t*)alloc(131072*2);
  ushort_t* w2h = (ushort_t*)alloc(65536*2);
  ushort_t* w2l = (ushort_t*)alloc(65536*2);
  float*    bias9 = (float*)alloc(9*FD*4);
  uint32_t* tab = (uint32_t*)alloc(NA*4);
  ushort_t* kh = (ushort_t*)alloc(HBYTES);
  ushort_t* kl = (ushort_t*)alloc(HBYTES);
  size_t offE = off;                 // logits region starts here (overlays xh, hh)
  char* E = alloc(2*HBYTES);         // xh [MT][512] bf16 (dead after l1)
  char* F = alloc(HBYTES);           // Pk|Pk2 (dead after xfeat), then hh (dead after l2)
  ushort_t* xh = (ushort_t*)E;
  float* Pk  = (float*)F;
  float* Pk2 = (float*)(F + (size_t)8*PB*4);
  ushort_t* hh = (ushort_t*)F;
  float* logits = (float*)(Wp + offE);

  // chunk size: how many batches of logits fit from offE to end of ws
  int c = 1;
  if (ws_size > offE + LBYTES) {
    size_t cap = (ws_size - offE) / LBYTES;
    c = (cap > 8) ? 8 : (int)cap;
    if (c < 1) c = 1;
  }

  k_rowsum<<<dim3(256), dim3(256), 0, stream>>>(k, v, Pk, Pk2, Pv);
  k_colsum<<<dim3(33, 8, 3), dim3(256), 0, stream>>>(Pk, Pk2, Pv);
  k_prep<<<dim3(1115), dim3(256), 0, stream>>>(q, W1, W2, eh, ew, b1,
      qh, ql, w1h, w1l, w2h, w2l, bias9, tab);
  k_xfeat<<<dim3((MT+15)/16), dim3(256), 0, stream>>>(Pk, Pk2, tab, xh);
  k_l1<<<dim3(541), dim3(512), 0, stream>>>(xh, w1h, w1l, bias9, tab, hh);
  k_l2<<<dim3(541), dim3(512), 0, stream>>>(hh, w2h, w2l, b2, kh, kl);
  for (int s0 = 0; s0 < 8; s0 += c) {
    int cc = (8 - s0 < c) ? (8 - s0) : c;
    k_logits<<<dim3(136*cc), dim3(1024), 0, stream>>>(qh, ql, kh, kl, logits, s0, 136*cc);
    k_final<<<dim3(1024*cc), dim3(512), 0, stream>>>(logits, Pv, tab, out, s0);
  }
}

// Round 19
// 458.632 us; speedup vs baseline: 1.0683x; 1.0683x over previous
//
#include <hip/hip_runtime.h>
#include <stdint.h>

#define FD   256
#define NA   8649
#define MT   69192          // 8*NA flattened rows
#define LSTR 8704
#define PB   (33*33*256)

typedef unsigned short ushort_t;
typedef short bf16x8 __attribute__((ext_vector_type(8)));
typedef float f32x4  __attribute__((ext_vector_type(4)));

#define SWZ(r) (((r) >> 2) & 3)

// ---------- bf16 helpers ----------
__device__ __forceinline__ unsigned short f2bf(float x) {
  unsigned int u = __float_as_uint(x);
  unsigned int r = (u + 0x7FFFu + ((u >> 16) & 1u)) >> 16;
  return (unsigned short)r;
}
__device__ __forceinline__ float bf2f(unsigned short h) {
  return __uint_as_float(((unsigned int)h) << 16);
}
__device__ __forceinline__ void dec2(float x, unsigned short& h, unsigned short& l) {
  h = f2bf(x);
  l = f2bf(x - bf2f(h));
}

__device__ __forceinline__ void gl2lds(const void* g, void* l) {
  __builtin_amdgcn_global_load_lds(
      (const __attribute__((address_space(1))) void*)g,
      (__attribute__((address_space(3))) void*)l, 16, 0, 0);
}

__device__ __forceinline__ bf16x8 fldq(const ushort_t* plane, int row, int qq) {
  return *(const bf16x8*)(plane + row*32 + ((qq ^ SWZ(row)) << 3));
}

__device__ __forceinline__ f32x4 mfma2(bf16x8 ah, bf16x8 bh, bf16x8 bl, f32x4 acc) {
  acc = __builtin_amdgcn_mfma_f32_16x16x32_bf16(ah, bl, acc, 0, 0, 0);
  acc = __builtin_amdgcn_mfma_f32_16x16x32_bf16(ah, bh, acc, 0, 0, 0);
  return acc;
}
__device__ __forceinline__ f32x4 mfma3(bf16x8 ah, bf16x8 al, bf16x8 bh, bf16x8 bl, f32x4 acc) {
  acc = __builtin_amdgcn_mfma_f32_16x16x32_bf16(al, bh, acc, 0, 0, 0);
  acc = __builtin_amdgcn_mfma_f32_16x16x32_bf16(ah, bl, acc, 0, 0, 0);
  acc = __builtin_amdgcn_mfma_f32_16x16x32_bf16(ah, bh, acc, 0, 0, 0);
  return acc;
}

// ================= integral images =================
__global__ __launch_bounds__(256) void k_rowsum(const float* __restrict__ kin,
    const float* __restrict__ vin, float* __restrict__ Pk,
    float* __restrict__ Pk2, float* __restrict__ Pv) {
  int b = blockIdx.x >> 5, i = blockIdx.x & 31;
  int f = threadIdx.x;
  const float* kr = kin + ((size_t)b*1024 + i*32)*FD + f;
  const float* vr = vin + ((size_t)b*1024 + i*32)*FD + f;
  float sk = 0.f, sk2 = 0.f, sv = 0.f;
  size_t base = (size_t)b*PB + (size_t)(i+1)*33*FD + f;
  #pragma unroll
  for (int j = 0; j < 32; ++j) {
    float kv = kr[j*FD], vv = vr[j*FD];
    sk += kv; sk2 += kv*kv; sv += vv;
    size_t p = base + (size_t)(j+1)*FD;
    Pk[p] = sk; Pk2[p] = sk2; Pv[p] = sv;
  }
}

__global__ __launch_bounds__(256) void k_colsum(float* __restrict__ Pk,
    float* __restrict__ Pk2, float* __restrict__ Pv) {
  int j = blockIdx.x, b = blockIdx.y, f = threadIdx.x;
  float* P = (blockIdx.z == 0) ? Pk : (blockIdx.z == 1) ? Pk2 : Pv;
  size_t base = (size_t)b*PB + f;
  if (j == 0) {
    for (int i = 0; i < 33; ++i) P[base + (size_t)i*33*FD] = 0.f;
  } else {
    P[base + (size_t)j*FD] = 0.f;
    float a = 0.f;
    for (int i = 1; i <= 32; ++i) {
      size_t p = base + ((size_t)i*33 + j)*FD;
      a += P[p]; P[p] = a;
    }
  }
}

// ============ merged prep: decompq | LDS-transposed decompw | bias9 | tab ============
__global__ __launch_bounds__(256) void k_prep(const float* __restrict__ q,
    const float* __restrict__ W1, const float* __restrict__ W2,
    const float* __restrict__ eh, const float* __restrict__ ew,
    const float* __restrict__ b1,
    ushort_t* __restrict__ qh, ushort_t* __restrict__ ql,
    ushort_t* __restrict__ w1h, ushort_t* __restrict__ w1l,
    ushort_t* __restrict__ w2h, ushort_t* __restrict__ w2l,
    float* __restrict__ bias9, uint32_t* __restrict__ tab) {
  __shared__ float tile[64][65];
  int bx = blockIdx.x, t = threadIdx.x;
  if (bx < 1024) {                       // ---- decompq ----
    int i = (bx*256 + t) * 8;
    float4 v0 = *(const float4*)(q + i);
    float4 v1 = *(const float4*)(q + i + 4);
    float e[8] = {v0.x, v0.y, v0.z, v0.w, v1.x, v1.y, v1.z, v1.w};
    bf16x8 h8, l8;
    #pragma unroll
    for (int j = 0; j < 8; ++j) {
      unsigned short hu, lu; dec2(e[j], hu, lu);
      h8[j] = (short)hu; l8[j] = (short)lu;
    }
    *(bf16x8*)(qh + i) = h8;
    *(bf16x8*)(ql + i) = l8;
  } else if (bx < 1072) {                // ---- decompw: 64x64 LDS transpose tiles ----
    int tb = bx - 1024;
    const float* src; ushort_t* dh; ushort_t* dl; int K, k0, n0;
    if (tb < 32) { src = W1; dh = w1h; dl = w1l; K = 512; k0 = (tb>>2)*64; n0 = (tb&3)*64; }
    else { tb -= 32; src = W2; dh = w2h; dl = w2l; K = 256; k0 = (tb>>2)*64; n0 = (tb&3)*64; }
    int c = t & 63, r4 = t >> 6;
    #pragma unroll
    for (int i = 0; i < 16; ++i) {
      int r = i*4 + r4;
      tile[r][c] = src[(size_t)(k0+r)*FD + n0 + c];
    }
    __syncthreads();
    #pragma unroll
    for (int i = 0; i < 16; ++i) {
      int n = i*4 + r4;
      float x = tile[c][n];
      unsigned short hu, lu; dec2(x, hu, lu);
      dh[(size_t)(n0+n)*K + k0 + c] = hu;
      dl[(size_t)(n0+n)*K + k0 + c] = lu;
    }
  } else if (bx < 1081) {                // ---- bias9 ----
    int s = bx - 1072, c = t;
    int ah = s/3, aw = s - ah*3;
    float acc = b1[c];
    for (int j = 0; j < 128; ++j) acc += eh[ah*128 + j] * W1[(size_t)(512+j)*FD + c];
    for (int j = 0; j < 128; ++j) acc += ew[aw*128 + j] * W1[(size_t)(640+j)*FD + c];
    bias9[s*FD + c] = acc;
  } else {                               // ---- tab ----
    int a = (bx - 1081)*256 + t;
    if (a >= NA) return;
    const int offs[10] = {0,1024,2016,2976,3968,4929,5859,6819,7749,8649};
    int s = 0;
    #pragma unroll
    for (int i = 1; i < 9; ++i) s += (a >= offs[i]) ? 1 : 0;
    int ah = s/3, aw = s - ah*3;
    int idx = a - offs[s];
    int wc = 32 - aw;
    int r = idx / wc;
    int c = idx - r*wc;
    tab[a] = (uint32_t)(r | (c<<6) | (ah<<12) | (aw<<14));
  }
}

// ================= X features: mean|std -> bf16 [MT][512] =================
__global__ __launch_bounds__(256) void k_xfeat(const float* __restrict__ Pk,
    const float* __restrict__ Pk2, const uint32_t* __restrict__ tab,
    ushort_t* __restrict__ xh) {
  int t = threadIdx.x;
  int row0 = blockIdx.x * 16;
  for (int rr = 0; rr < 16; ++rr) {
    int gr = row0 + rr;
    if (gr >= MT) return;
    int bi = gr / NA;
    int a  = gr - bi*NA;
    uint32_t tb = tab[a];
    int r1 = tb & 63, c1 = (tb>>6)&63, ah=(tb>>12)&3, aw=(tb>>14)&3;
    int r2 = r1+ah+1, c2 = c1+aw+1;
    const float* PKb  = Pk  + (size_t)bi*PB + t;
    const float* PK2b = Pk2 + (size_t)bi*PB + t;
    int i11=(r1*33+c1)*FD, i12=(r1*33+c2)*FD, i21=(r2*33+c1)*FD, i22=(r2*33+c2)*FD;
    float s  = PKb[i22]  - PKb[i12]  - PKb[i21]  + PKb[i11];
    float s2 = PK2b[i22] - PK2b[i12] - PK2b[i21] + PK2b[i11];
    float inv = 1.0f/(float)((ah+1)*(aw+1));
    float mean = s * inv;
    float sd = sqrtf(fabsf(s2*inv - mean*mean) + 1e-6f);
    xh[(size_t)gr*512 + t]       = f2bf(mean);
    xh[(size_t)gr*512 + 256 + t] = f2bf(sd);
  }
}

// ================= l1: h = relu(X @ W1t + bias9), BM=128 BN=256 BK=32, 512thr =================
__global__ __launch_bounds__(512) void k_l1(
    const ushort_t* __restrict__ xh, const ushort_t* __restrict__ w1h,
    const ushort_t* __restrict__ w1l, const float* __restrict__ bias9g,
    const uint32_t* __restrict__ tab, ushort_t* __restrict__ hh) {
  __shared__ __align__(16) char SM[81920];     // 2 bufs x (A 8K + BH 16K + BL 16K)
  ushort_t* SU = (ushort_t*)SM;
  int t = threadIdx.x, lane = t & 63, wid = t >> 6;
  int wr = wid >> 2, wc = wid & 3;
  int row0 = blockIdx.x * 128;

  auto stage = [&](int s, int kc) {
    ushort_t* base = SU + s*20480;
    int r = wid*16 + (lane >> 2);
    int q = lane & 3;
    int rr = row0 + r; if (rr > MT-1) rr = MT-1;
    gl2lds(xh + (size_t)rr*512 + kc + ((q ^ SWZ(r)) << 3), base + wid*512);
    #pragma unroll
    for (int i = 0; i < 2; ++i) {
      int g = 2*wid + i;
      int r2 = g*16 + (lane >> 2);
      int off = (q ^ SWZ(r2)) << 3;
      gl2lds(w1h + (size_t)r2*512 + kc + off, base + 4096  + g*512);
      gl2lds(w1l + (size_t)r2*512 + kc + off, base + 12288 + g*512);
    }
  };

  f32x4 acc[4][4];
  #pragma unroll
  for (int i = 0; i < 4; ++i)
    #pragma unroll
    for (int j = 0; j < 4; ++j) acc[i][j] = (f32x4)0.f;

  stage(0, 0);
  __syncthreads();
  int cur = 0;
  for (int step = 0; step < 16; ++step) {
    if (step < 15) stage(cur ^ 1, (step+1)*32);
    const ushort_t* SA  = SU + cur*20480;
    const ushort_t* SBH = SA + 4096;
    const ushort_t* SBL = SA + 12288;
    int qq = lane >> 4;
    bf16x8 a_[4], bh_[4], bl_[4];
    #pragma unroll
    for (int i = 0; i < 4; ++i) {
      a_[i]  = fldq(SA,  wr*64 + i*16 + (lane & 15), qq);
      bh_[i] = fldq(SBH, wc*64 + i*16 + (lane & 15), qq);
      bl_[i] = fldq(SBL, wc*64 + i*16 + (lane & 15), qq);
    }
    #pragma unroll
    for (int mt = 0; mt < 4; ++mt)
      #pragma unroll
      for (int nt = 0; nt < 4; ++nt)
        acc[mt][nt] = mfma2(a_[mt], bh_[nt], bl_[nt], acc[mt][nt]);
    if (step < 15) { __syncthreads(); cur ^= 1; }
  }

  #pragma unroll
  for (int mt = 0; mt < 4; ++mt) {
    int lrowb = wr*64 + mt*16 + (lane >> 4)*4;
    #pragma unroll
    for (int r = 0; r < 4; ++r) {
      int grow = row0 + lrowb + r;
      if (grow < MT) {
        int a = grow % NA;
        uint32_t tb = tab[a];
        int seg = ((tb>>12)&3)*3 + ((tb>>14)&3);
        const float* bseg = bias9g + seg*FD;
        #pragma unroll
        for (int nt = 0; nt < 4; ++nt) {
          int col = wc*64 + nt*16 + (lane & 15);
          float hv = fmaxf(acc[mt][nt][r] + bseg[col], 0.f);
          hh[(size_t)grow*FD + col] = f2bf(hv);
        }
      }
    }
  }
}

// ================= l2: k_area = h @ W2t + b2 -> hi/lo, BM=128 BN=256 =================
__global__ __launch_bounds__(512) void k_l2(
    const ushort_t* __restrict__ hh, const ushort_t* __restrict__ w2h,
    const ushort_t* __restrict__ w2l, const float* __restrict__ b2,
    ushort_t* __restrict__ kh, ushort_t* __restrict__ kl) {
  __shared__ __align__(16) char SM[81920];
  ushort_t* SU = (ushort_t*)SM;
  int t = threadIdx.x, lane = t & 63, wid = t >> 6;
  int wr = wid >> 2, wc = wid & 3;
  int row0 = blockIdx.x * 128;

  auto stage = [&](int s, int kc) {
    ushort_t* base = SU + s*20480;
    int r = wid*16 + (lane >> 2);
    int q = lane & 3;
    int rr = row0 + r; if (rr > MT-1) rr = MT-1;
    gl2lds(hh + (size_t)rr*FD + kc + ((q ^ SWZ(r)) << 3), base + wid*512);
    #pragma unroll
    for (int i = 0; i < 2; ++i) {
      int g = 2*wid + i;
      int r2 = g*16 + (lane >> 2);
      int off = (q ^ SWZ(r2)) << 3;
      gl2lds(w2h + (size_t)r2*FD + kc + off, base + 4096  + g*512);
      gl2lds(w2l + (size_t)r2*FD + kc + off, base + 12288 + g*512);
    }
  };

  f32x4 acc[4][4];
  #pragma unroll
  for (int i = 0; i < 4; ++i)
    #pragma unroll
    for (int j = 0; j < 4; ++j) acc[i][j] = (f32x4)0.f;

  stage(0, 0);
  __syncthreads();
  int cur = 0;
  for (int step = 0; step < 8; ++step) {
    if (step < 7) stage(cur ^ 1, (step+1)*32);
    const ushort_t* SA  = SU + cur*20480;
    const ushort_t* SBH = SA + 4096;
    const ushort_t* SBL = SA + 12288;
    int qq = lane >> 4;
    bf16x8 a_[4], bh_[4], bl_[4];
    #pragma unroll
    for (int i = 0; i < 4; ++i) {
      a_[i]  = fldq(SA,  wr*64 + i*16 + (lane & 15), qq);
      bh_[i] = fldq(SBH, wc*64 + i*16 + (lane & 15), qq);
      bl_[i] = fldq(SBL, wc*64 + i*16 + (lane & 15), qq);
    }
    #pragma unroll
    for (int mt = 0; mt < 4; ++mt)
      #pragma unroll
      for (int nt = 0; nt < 4; ++nt)
        acc[mt][nt] = mfma2(a_[mt], bh_[nt], bl_[nt], acc[mt][nt]);
    if (step < 7) { __syncthreads(); cur ^= 1; }
  }

  #pragma unroll
  for (int mt = 0; mt < 4; ++mt) {
    int lrowb = wr*64 + mt*16 + (lane >> 4)*4;
    #pragma unroll
    for (int r = 0; r < 4; ++r) {
      int grow = row0 + lrowb + r;
      if (grow < MT) {
        #pragma unroll
        for (int nt = 0; nt < 4; ++nt) {
          int col = wc*64 + nt*16 + (lane & 15);
          float kv = acc[mt][nt][r] + b2[col];
          unsigned short hu, lu; dec2(kv, hu, lu);
          kh[(size_t)grow*FD + col] = hu;
          kl[(size_t)grow*FD + col] = lu;
        }
      }
    }
  }
}

// === logits: q @ k_area^T, 3-term, 256x256 tile BK=32 dbuf, -inf pad, XCD swizzle ===
__global__ __launch_bounds__(512, 2) void k_logits(
    const ushort_t* __restrict__ qh, const ushort_t* __restrict__ ql,
    const ushort_t* __restrict__ kh, const ushort_t* __restrict__ kl,
    float* __restrict__ logits, int bbase, int nwg) {
  __shared__ __align__(16) ushort_t SU[2][32768];  // 64KB/buf: Ah|Al|Bh|Bl (8192 each)
  int t = threadIdx.x, lane = t & 63, wid = t >> 6;
  int wr = wid >> 2, wc = wid & 3;                 // 2x4 wave grid, 128x64 per wave
  // XCD-aware bijective swizzle (nwg = 136*cc, always % 8 == 0)
  int bx0 = blockIdx.x;
  int bx = (bx0 & 7) * (nwg >> 3) + (bx0 >> 3);
  int bc = bx / 136;
  int r5 = bx - bc*136;
  int mb = r5 / 34, ab = r5 - mb*34;
  int m0 = mb*256, a0 = ab*256;
  int b = bbase + bc;
  size_t qbase = (size_t)b*1024*FD;
  size_t kbase = (size_t)b*NA*FD;
  float* logW = logits + (size_t)bc*1024*LSTR;

  auto stage = [&](int s, int kc) {
    ushort_t* base = &SU[s][0];
    #pragma unroll
    for (int g2 = 0; g2 < 2; ++g2) {
      int g = wid*2 + g2;                 // wave-load 0..15 per plane
      int ch = g*64 + lane;               // chunk id (1024 per plane)
      int rr = ch >> 2, sl = ch & 3;
      int off = (sl ^ SWZ(rr)) << 3;
      gl2lds(qh + qbase + (size_t)(m0+rr)*FD + kc + off, base + g*512);
      gl2lds(ql + qbase + (size_t)(m0+rr)*FD + kc + off, base + 8192 + g*512);
      int ar = a0 + rr; if (ar > NA-1) ar = NA-1;
      gl2lds(kh + kbase + (size_t)ar*FD + kc + off, base + 16384 + g*512);
      gl2lds(kl + kbase + (size_t)ar*FD + kc + off, base + 24576 + g*512);
    }
  };

  f32x4 acc[8][4];
  #pragma unroll
  for (int i = 0; i < 8; ++i)
    #pragma unroll
    for (int j = 0; j < 4; ++j) acc[i][j] = (f32x4)0.f;

  stage(0, 0);
  __syncthreads();
  int cur = 0;
  for (int step = 0; step < 8; ++step) {
    if (step < 7) stage(cur ^ 1, (step+1)*32);
    const ushort_t* Ah = &SU[cur][0];
    const ushort_t* Al = Ah + 8192;
    const ushort_t* Bh = Ah + 16384;
    const ushort_t* Bl = Ah + 24576;
    int qq = lane >> 4;
    bf16x8 bhf[4], blf[4];
    #pragma unroll
    for (int nt = 0; nt < 4; ++nt) {
      int rb = wc*64 + nt*16 + (lane & 15);
      bhf[nt] = fldq(Bh, rb, qq);
      blf[nt] = fldq(Bl, rb, qq);
    }
    #pragma unroll
    for (int mt = 0; mt < 8; ++mt) {
      int ra = wr*128 + mt*16 + (lane & 15);
      bf16x8 ahf = fldq(Ah, ra, qq);
      bf16x8 alf = fldq(Al, ra, qq);
      #pragma unroll
      for (int nt = 0; nt < 4; ++nt)
        acc[mt][nt] = mfma3(ahf, alf, bhf[nt], blf[nt], acc[mt][nt]);
    }
    if (step < 7) { __syncthreads(); cur ^= 1; }
  }

  const float NINF = -__builtin_inff();
  #pragma unroll
  for (int mt = 0; mt < 8; ++mt) {
    int m = m0 + wr*128 + mt*16 + (lane >> 4)*4;
    #pragma unroll
    for (int nt = 0; nt < 4; ++nt) {
      int col = a0 + wc*64 + nt*16 + (lane & 15);
      bool ok = (col < NA);
      #pragma unroll
      for (int r = 0; r < 4; ++r)
        logW[(size_t)(m+r)*LSTR + col] = ok ? acc[mt][nt][r] : NINF;
    }
  }
}

// ====== final: 512-thr float bucketed top-64 (SCALE=8) + 8-group float4 PV ======
__device__ __forceinline__ uint32_t f2key(float x) {
  uint32_t u = __float_as_uint(x);
  return (u & 0x80000000u) ? ~u : (u | 0x80000000u);
}
__device__ __forceinline__ float key2f(uint32_t k) {
  uint32_t u = (k & 0x80000000u) ? (k & 0x7FFFFFFFu) : ~k;
  return __uint_as_float(u);
}

__global__ __launch_bounds__(512) void k_final(const float* __restrict__ logits,
    const float* __restrict__ Pv, const uint32_t* __restrict__ tab,
    float* __restrict__ outp, int bbase) {
  __shared__ int   hist[256];
  __shared__ float redf[8];
  __shared__ int   seli[2];
  __shared__ int   lst[192];
  __shared__ float lw[192];
  __shared__ int4  offs[192];
  __shared__ float accvB[8][256];
  __shared__ int   shcnt;
  __shared__ float cands_v[256];
  __shared__ int   cands_i[256];
  __shared__ int   ncand;
  __shared__ float thrs;
  int t = threadIdx.x;
  int qrow = blockIdx.x & 1023;
  int bc = blockIdx.x >> 10;
  int b = bbase + bc;
  const float* row = logits + ((size_t)bc*1024 + qrow)*LSTR;

  // ---- vectorized row load: v[4j+k] = row[j*2048 + 4t + k], v[16] = row[8192+t] ----
  float v[17];
  {
    const float4* row4 = (const float4*)row;
    float4 x0 = row4[t], x1 = row4[t+512], x2 = row4[t+1024], x3 = row4[t+1536];
    v[0]=x0.x; v[1]=x0.y; v[2]=x0.z; v[3]=x0.w;
    v[4]=x1.x; v[5]=x1.y; v[6]=x1.z; v[7]=x1.w;
    v[8]=x2.x; v[9]=x2.y; v[10]=x2.z; v[11]=x2.w;
    v[12]=x3.x; v[13]=x3.y; v[14]=x3.z; v[15]=x3.w;
    v[16]=row[8192 + t];
  }
  float vmax = v[0];
  #pragma unroll
  for (int i = 1; i < 17; ++i) vmax = fmaxf(vmax, v[i]);
  #pragma unroll
  for (int off = 32; off >= 1; off >>= 1) vmax = fmaxf(vmax, __shfl_xor(vmax, off));
  if ((t & 63) == 0) redf[t >> 6] = vmax;
  if (t < 256) hist[t] = 0;
  if (t == 0) { seli[0] = -1; ncand = 0; shcnt = 0; }
  __syncthreads();
  float maxv = fmaxf(fmaxf(fmaxf(redf[0],redf[1]),fmaxf(redf[2],redf[3])),
                     fmaxf(fmaxf(redf[4],redf[5]),fmaxf(redf[6],redf[7])));

  // ---- pass 1: near-max bucketed histogram (bin width 1/8, range maxv-32..maxv) ----
  const float SCALE = 8.0f;
  int bins[17];
  #pragma unroll
  for (int i = 0; i < 17; ++i) {
    int bin = (int)((maxv - v[i]) * SCALE);
    bins[i] = bin;
    if ((unsigned)bin < 256u) atomicAdd(&hist[bin], 1);
  }
  __syncthreads();
  // ---- scan: first bin where cumulative >= 64; rank within bin ----
  if (t < 64) {
    int b0 = t*4;
    int h0 = hist[b0], h1 = hist[b0+1], h2 = hist[b0+2], h3 = hist[b0+3];
    int gsum = h0+h1+h2+h3;
    int pre = gsum;
    #pragma unroll
    for (int d = 1; d < 64; d <<= 1) {
      int o = __shfl_up(pre, d);
      if (t >= d) pre += o;
    }
    pre -= gsum;                         // exclusive prefix (bins < b0)
    int c0 = pre+h0, c1 = c0+h1, c2 = c1+h2, c3 = c2+h3;
    int cc[4] = {c0, c1, c2, c3};
    int pv[4] = {pre, c0, c1, c2};
    #pragma unroll
    for (int j = 0; j < 4; ++j)
      if (cc[j] >= 64 && pv[j] < 64) { seli[0] = b0 + j; seli[1] = 64 - pv[j]; }
  }
  __syncthreads();
  int tb_bin = seli[0];
  int nc_bin = (tb_bin >= 0) ? hist[tb_bin] : 1000;
  bool fast = (tb_bin >= 0) && (nc_bin <= 256);
  if (fast) {
    int rnk = seli[1];
    // ---- merged collect: bins<tb selected directly; bin==tb -> candidates ----
    #pragma unroll
    for (int i = 0; i < 17; ++i) {
      int idx = (i < 16) ? ((i >> 2)*2048 + 4*t + (i & 3)) : (8192 + t);
      if (bins[i] < tb_bin) {
        int p = atomicAdd(&shcnt, 1);
        if (p < 192) { lst[p] = idx; lw[p] = expf(v[i] - maxv); }
      } else if (bins[i] == tb_bin) {
        int p = atomicAdd(&ncand, 1);
        cands_v[p] = v[i]; cands_i[p] = idx;
      }
    }
    __syncthreads();
    // ---- exact rank among candidates: thr = rnk-th largest ----
    if (t < nc_bin) {
      float ck = cands_v[t];
      int ge = 0, gt = 0;
      for (int j = 0; j < nc_bin; ++j) {
        float cj = cands_v[j];
        ge += (cj >= ck) ? 1 : 0;
        gt += (cj >  ck) ? 1 : 0;
      }
      if (ge >= rnk && gt < rnk) thrs = ck;
    }
    __syncthreads();
    float thrf = thrs;
    // ---- append candidates >= thr (tiny pass over nc only) ----
    for (int j = t; j < nc_bin; j += 512) {
      if (cands_v[j] >= thrf) {
        int p = atomicAdd(&shcnt, 1);
        if (p < 192) { lst[p] = cands_i[j]; lw[p] = expf(cands_v[j] - maxv); }
      }
    }
  } else {
    // ---- fallback: full radix-256 select on monotone keys ----
    uint32_t prefix = 0; int need = 64;
    for (int rd = 0; rd < 4; ++rd) {
      int shift = 24 - rd*8;
      uint32_t pmask = (rd == 0) ? 0u : (0xFFFFFFFFu << (shift + 8));
      if (t < 256) hist[t] = 0;
      __syncthreads();
      #pragma unroll
      for (int i = 0; i < 17; ++i) {
        uint32_t ky = f2key(v[i]);
        if ((ky & pmask) == prefix)
          atomicAdd(&hist[(ky >> shift) & 255], 1);
      }
      __syncthreads();
      if (t < 64) {
        int b0 = t*4;
        int h0 = hist[b0], h1 = hist[b0+1], h2 = hist[b0+2], h3 = hist[b0+3];
        int s3 = h3, s2 = h2 + s3, s1 = h1 + s2, s0 = h0 + s1;
        int suf = s0;
        #pragma unroll
        for (int d = 1; d < 64; d <<= 1) {
          int o = __shfl_down(suf, d);
          if (t + d < 64) suf += o;
        }
        int above = suf - s0;
        int cg[5] = { above + s0, above + s1, above + s2, above + s3, above };
        #pragma unroll
        for (int j = 0; j < 4; ++j)
          if (cg[j] >= need && cg[j+1] < need) { seli[0] = b0 + j; seli[1] = need - cg[j+1]; }
      }
      __syncthreads();
      prefix |= ((uint32_t)seli[0]) << shift;
      need = seli[1];
      __syncthreads();
    }
    float thrf = key2f(prefix);
    #pragma unroll
    for (int i = 0; i < 17; ++i) {
      if (v[i] >= thrf) {
        int p = atomicAdd(&shcnt, 1);
        if (p < 192) {
          int idx = (i < 16) ? ((i >> 2)*2048 + 4*t + (i & 3)) : (8192 + t);
          lst[p] = idx;
          lw[p]  = expf(v[i] - maxv);
        }
      }
    }
  }
  __syncthreads();
  int S = min(shcnt, 192);
  // ---- one-time offset precompute (t<S) + weight sum (t<64) ----
  if (t < S) {
    int a = lst[t];
    uint32_t tb = tab[a];
    int r1 = tb & 63, c1 = (tb>>6)&63, ah=(tb>>12)&3, aw=(tb>>14)&3;
    int r2 = r1+ah+1, c2 = c1+aw+1;
    offs[t] = make_int4((r1*33+c1)*FD, (r1*33+c2)*FD, (r2*33+c1)*FD, (r2*33+c2)*FD);
  }
  float ssum = 0.f;
  if (t < 64) {
    for (int i = t; i < S; i += 64) ssum += lw[i];
    #pragma unroll
    for (int off = 32; off >= 1; off >>= 1) ssum += __shfl_xor(ssum, off);
    if (t == 0) redf[0] = ssum;
  }
  __syncthreads();
  float inv = 1.0f / redf[0];
  // ---- PV gather: 8 wave-groups, float4 per lane, 2x unrolled ----
  int lf  = (t & 63) << 2;       // f base (float4)
  int grp = t >> 6;              // 0..7 (one wave per group)
  const float* Pvb = Pv + (size_t)b*PB + lf;
  float4 a4 = make_float4(0.f, 0.f, 0.f, 0.f);
  auto body = [&](int i) {
    int4 o = offs[i];
    float w = lw[i];
    float4 A = *(const float4*)(Pvb + o.x);
    float4 B = *(const float4*)(Pvb + o.y);
    float4 C = *(const float4*)(Pvb + o.z);
    float4 D = *(const float4*)(Pvb + o.w);
    a4.x += w * (D.x - B.x - C.x + A.x);
    a4.y += w * (D.y - B.y - C.y + A.y);
    a4.z += w * (D.z - B.z - C.z + A.z);
    a4.w += w * (D.w - B.w - C.w + A.w);
  };
  int i = grp;
  for (; i + 8 < S; i += 16) { body(i); body(i + 8); }
  if (i < S) body(i);
  *(float4*)&accvB[grp][lf] = a4;
  __syncthreads();
  if (t < 256) {
    float s = 0.f;
    #pragma unroll
    for (int g = 0; g < 8; ++g) s += accvB[g][t];
    outp[((size_t)b*1024 + qrow)*FD + t] = s * inv;
  }
}

// ================= launch =================
extern "C" void kernel_launch(void* const* d_in, const int* in_sizes, int n_in,
                              void* d_out, int out_size, void* d_ws, size_t ws_size,
                              hipStream_t stream) {
  const float* q  = (const float*)d_in[0];
  const float* k  = (const float*)d_in[1];
  const float* v  = (const float*)d_in[2];
  const float* eh = (const float*)d_in[3];
  const float* ew = (const float*)d_in[4];
  const float* W1 = (const float*)d_in[5];
  const float* b1 = (const float*)d_in[6];
  const float* W2 = (const float*)d_in[7];
  const float* b2 = (const float*)d_in[8];
  float* out = (float*)d_out;

  char* Wp = (char*)d_ws;
  size_t off = 0;
  auto alloc = [&](size_t bytes) -> char* {
    char* p = Wp + off; off += (bytes + 255) & ~(size_t)255; return p;
  };
  const size_t HBYTES = (size_t)MT*FD*2;        // 35,426,304
  const size_t LBYTES = (size_t)1024*LSTR*4;    // 35,651,584 per batch
  float*    Pv  = (float*)alloc((size_t)8*PB*4);
  ushort_t* qh  = (ushort_t*)alloc((size_t)8*1024*FD*2);
  ushort_t* ql  = (ushort_t*)alloc((size_t)8*1024*FD*2);
  ushort_t* w1h = (ushort_t*)alloc(131072*2);
  ushort_t* w1l = (ushort_t*)alloc(131072*2);
  ushort_t* w2h = (ushort_t*)alloc(65536*2);
  ushort_t* w2l = (ushort_t*)alloc(65536*2);
  float*    bias9 = (float*)alloc(9*FD*4);
  uint32_t* tab = (uint32_t*)alloc(NA*4);
  ushort_t* kh = (ushort_t*)alloc(HBYTES);
  ushort_t* kl = (ushort_t*)alloc(HBYTES);
  size_t offE = off;                 // logits region starts here (overlays xh, hh)
  char* E = alloc(2*HBYTES);         // xh [MT][512] bf16 (dead after l1)
  char* F = alloc(HBYTES);           // Pk|Pk2 (dead after xfeat), then hh (dead after l2)
  ushort_t* xh = (ushort_t*)E;
  float* Pk  = (float*)F;
  float* Pk2 = (float*)(F + (size_t)8*PB*4);
  ushort_t* hh = (ushort_t*)F;
  float* logits = (float*)(Wp + offE);

  // chunk size: how many batches of logits fit from offE to end of ws
  int c = 1;
  if (ws_size > offE + LBYTES) {
    size_t cap = (ws_size - offE) / LBYTES;
    c = (cap > 8) ? 8 : (int)cap;
    if (c < 1) c = 1;
  }

  k_rowsum<<<dim3(256), dim3(256), 0, stream>>>(k, v, Pk, Pk2, Pv);
  k_colsum<<<dim3(33, 8, 3), dim3(256), 0, stream>>>(Pk, Pk2, Pv);
  k_prep<<<dim3(1115), dim3(256), 0, stream>>>(q, W1, W2, eh, ew, b1,
      qh, ql, w1h, w1l, w2h, w2l, bias9, tab);
  k_xfeat<<<dim3((MT+15)/16), dim3(256), 0, stream>>>(Pk, Pk2, tab, xh);
  k_l1<<<dim3(541), dim3(512), 0, stream>>>(xh, w1h, w1l, bias9, tab, hh);
  k_l2<<<dim3(541), dim3(512), 0, stream>>>(hh, w2h, w2l, b2, kh, kl);
  for (int s0 = 0; s0 < 8; s0 += c) {
    int cc = (8 - s0 < c) ? (8 - s0) : c;
    k_logits<<<dim3(136*cc), dim3(512), 0, stream>>>(qh, ql, kh, kl, logits, s0, 136*cc);
    k_final<<<dim3(1024*cc), dim3(512), 0, stream>>>(logits, Pv, tab, out, s0);
  }
}